// Round 9
// baseline (2290.850 us; speedup 1.0000x reference)
//
#include <hip/hip_runtime.h>
#include <cstdint>
#include <cstddef>

#define DD 12
#define NNODE 32768
#define LTOK 3
#define KCH 4
#define HD 128
#define NC_STEP 896
#define KD_STEP 640
#define NC_EMB 128
#define KD_EMB 384

typedef unsigned short u16;
typedef __attribute__((ext_vector_type(8))) __bf16 bf16x8;
typedef __attribute__((ext_vector_type(4))) float f32x4;

__device__ __forceinline__ float bf2f(unsigned int u) {
  union { unsigned int i; float f; } v; v.i = (u & 0xffffu) << 16; return v.f;
}
__device__ __forceinline__ u16 f2bf(float f) {
  union { float f; unsigned int i; } v; v.f = f;
  unsigned int x = v.i;
  return (u16)((x + 0x7fffu + ((x >> 16) & 1u)) >> 16);
}
__device__ __forceinline__ float sigm(float x) { return 1.f / (1.f + __expf(-x)); }
__device__ __forceinline__ float tanh_fast(float x) { return 1.f - 2.f / (1.f + __expf(2.f * x)); }
__device__ __forceinline__ void async16(const void* g, void* l) {
  __builtin_amdgcn_global_load_lds((const __attribute__((address_space(1))) unsigned int*)g,
                                   (__attribute__((address_space(3))) unsigned int*)l, 16, 0, 0);
}

// ---------------------------------------------------------------------------
// R17 step GEMM: pre[32768,896] = A[32768,640] @ Ubig[896,640]^T + bias.
// R8 post-mortem: conflicts 4.59M -> 0 (8-lane-phase bank model verified)
// but dur unchanged -> LDS off the critical path; kernel is convoy/latency
// bound with avg occupancy only ~1.2 blocks/CU (30%). Session pattern:
// occupancy/parameter moves on this template win (R3, R6). So: 3 blocks/CU.
// BM 256->128, 256 thr / 4 waves (each still 64x64 out = 16 MFMA/barrier,
// preserving per-barrier compute density - avoids the R2 failure).
// 3 buffers x (A 8KB + B 8KB) = 48 KB -> 3 blocks/CU (144 KB).
// Rhythm frozen from R6/R8: per K-tile, stage(t+2) issue-early (4 async16:
// 2 A-slabs + 2 B-slabs of 16 rows), 8 ds_read_b128, 16 MFMA w/ setprio,
// belt vmcnt(4) (leaves S(t+2) in flight, never drain-to-0), ONE s_barrier.
// Ledger: S(t+1) issued at t-1; vmcnt(4) at end of t drains it (FIFO leaves
// the 4 just-issued S(t+2)); barrier = cross-wave visibility. WAR: S(t+2)
// targets buf[(t+2)%3], readers (t-1) done before barrier t-1.
// Swizzle (R8-verified, conflict count 0): 64B rows, phys 16B slot s of
// row r holds global chunk s ^ ((r>>1)&3).
//   stage: lane L -> row L>>2, slot L&3 -> global chunk (L&3)^((L>>3)&3)
//   read:  chunk q at row (..+(L&15)) -> phys slot q ^ ((L>>1)&3)
// Grid: 1792 blocks = 8 * 224 bijective XCD chunks, col-tile fastest
// (A-panel reused across the 7 col-tiles inside one XCD's L2); finer
// blocks also halve the end-tail skew.
// ---------------------------------------------------------------------------
#define BM 128
#define BN 128
#define BK 32

__global__ __launch_bounds__(256, 3) void gemm8_k(
    const u16* __restrict__ Abf, const u16* __restrict__ Tbf,
    const int* __restrict__ gidx, const u16* __restrict__ B,
    const float* __restrict__ bias, u16* __restrict__ outb,
    const u16* __restrict__ zbuf)
{
  __shared__ u16 As[3][BM * BK];   // 3 x 8 KB
  __shared__ u16 Bs[3][BN * BK];   // 3 x 8 KB
  const int t = threadIdx.x;
  const int w = t >> 6;            // 0..3
  const int L = t & 63;
  const int q = L >> 4;            // 0..3 : k-chunk this lane's MFMA frag uses
  const int r16 = L >> 2;          // 0..15 : row within 16-row stage slab
  const int sub = L & 3;           // 16B landing slot within 64B row
  const int swz = sub ^ ((L >> 3) & 3);   // global chunk this lane fetches
                                          // (= sub ^ ((row>>1)&3), row=L>>2)

  // bijective chunked XCD swizzle: 1792 = 8 * 224; col-tile fastest in chunk
  const int bid = blockIdx.x;
  const int wg = (bid & 7) * 224 + (bid >> 3);
  const int rt = wg / 7;
  const int ct = wg - rt * 7;
  const int row0 = rt * BM;
  const int col0 = ct * BN;

  const int wm = w >> 1;           // 0..1 : 64-row group
  const int wn = w & 1;            // 0..1 : 64-col group
  const int mrow = wm * 64;
  const int ncol = wn * 64;

  f32x4 acc[4][4];
#pragma unroll
  for (int a = 0; a < 4; ++a)
#pragma unroll
    for (int b = 0; b < 4; ++b)
      acc[a][b] = f32x4{0.f, 0.f, 0.f, 0.f};

  // gather indices: wave stages A rows w*32 + j*16 + r16, j=0,1
  int4 cidx[2];
#pragma unroll
  for (int j = 0; j < 2; ++j)
    cidx[j] = *(const int4*)&gidx[(row0 + w * 32 + j * 16 + r16) * KCH];

  // stage k-chunk [k0,k0+32) into buffer sel: 2 A + 2 B async16 per wave
  auto stageAll = [&](const int k0, const int sel) {
#pragma unroll
    for (int j = 0; j < 2; ++j) {
      const int rbase = w * 32 + j * 16;     // 16-row A slab
      const u16* src;
      if (k0 < 4 * HD) {
        const int id = ((const int*)&cidx[j])[k0 >> 7];
        const u16* base = (id >= 1) ? (Abf + (size_t)(id - 1) * HD) : zbuf;
        src = base + (k0 & 127) + swz * 8;
      } else {
        src = Tbf + (size_t)(row0 + rbase + r16) * HD + (k0 - 4 * HD) + swz * 8;
      }
      async16(src, &As[sel][rbase * BK]);
    }
#pragma unroll
    for (int j = 0; j < 2; ++j) {
      const int rb = w * 32 + j * 16;        // 16-row B slab
      async16(B + (size_t)(col0 + rb + r16) * KD_STEP + k0 + swz * 8,
              &Bs[sel][rb * BK]);
    }
  };

  // prologue: stage tiles 0,1 (8 instrs); wait tile 0 only
  stageAll(0, 0);
  stageAll(32, 1);
  asm volatile("s_waitcnt vmcnt(4)" ::: "memory");
  __builtin_amdgcn_sched_barrier(0);
  __builtin_amdgcn_s_barrier();
  __builtin_amdgcn_sched_barrier(0);

  constexpr int NT = KD_STEP / BK;   // 20
#pragma unroll
  for (int tt = 0; tt < NT; ++tt) {
    const int rd = tt % 3;
    // issue-early: tile t+2 staging (its buffer's readers done at barrier t-1)
    if (tt + 2 < NT) stageAll((tt + 2) * BK, (tt + 2) % 3);

    // fragment reads: phys slot = q ^ ((row>>1)&3), row bits from L&15
    const int pc = (q ^ ((L >> 1) & 3)) * 8;
    bf16x8 af[4], bfv[4];
#pragma unroll
    for (int mt = 0; mt < 4; ++mt)
      af[mt] = *(const bf16x8*)&As[rd][(mrow + mt * 16 + (L & 15)) * BK + pc];
#pragma unroll
    for (int nt = 0; nt < 4; ++nt)
      bfv[nt] = *(const bf16x8*)&Bs[rd][(ncol + nt * 16 + (L & 15)) * BK + pc];

    __builtin_amdgcn_s_setprio(1);
#pragma unroll
    for (int mt = 0; mt < 4; ++mt)
#pragma unroll
      for (int nt = 0; nt < 4; ++nt)
        acc[mt][nt] = __builtin_amdgcn_mfma_f32_16x16x32_bf16(
            af[mt], bfv[nt], acc[mt][nt], 0, 0, 0);
    __builtin_amdgcn_s_setprio(0);

    // tile-end sync: counted vmcnt (leaves S(t+2) in flight) + ONE barrier
    if (tt < NT - 1) {
      if (tt + 2 < NT) asm volatile("s_waitcnt vmcnt(4)" ::: "memory");
      else             asm volatile("s_waitcnt vmcnt(0)" ::: "memory");
      __builtin_amdgcn_sched_barrier(0);
      __builtin_amdgcn_s_barrier();
      __builtin_amdgcn_sched_barrier(0);
    }
  }

  // epilogue: C/D layout col=lane&15, row=(lane>>4)*4+i
#pragma unroll
  for (int nt = 0; nt < 4; ++nt) {
    const int col = col0 + ncol + nt * 16 + (L & 15);
    const float bb = bias[col];
#pragma unroll
    for (int mt = 0; mt < 4; ++mt) {
#pragma unroll
      for (int i = 0; i < 4; ++i) {
        const int row = row0 + mrow + mt * 16 + q * 4 + i;
        outb[(size_t)row * NC_STEP + col] = f2bf(acc[mt][nt][i] + bb);
      }
    }
  }
}

// ---------------------------------------------------------------------------
// Embed GEMM (R0-proven single-buffer structure):
// tslice[f32] & tbf[bf16] = gather(Ebf, tokens) @ Lbf^T + lin_b
// ---------------------------------------------------------------------------
__global__ __launch_bounds__(256) void gemm_emb_k(
    const u16* __restrict__ Ebf, const int* __restrict__ tokd,
    const u16* __restrict__ Lbf, const float* __restrict__ bias,
    float* __restrict__ outf, u16* __restrict__ outb)
{
  __shared__ u16 As[128 * 64];
  __shared__ u16 Bs[128 * 64];
  const int t = threadIdx.x;
  const int w = t >> 6;
  const int L = t & 63;
  const int q = L >> 4;
  const int lrow8 = L >> 3;
  const int sub = L & 7;
  const int swz = sub ^ lrow8;
  const int row0 = blockIdx.x * 128;

  f32x4 acc[4][4];
#pragma unroll
  for (int a = 0; a < 4; ++a)
#pragma unroll
    for (int b = 0; b < 4; ++b)
      acc[a][b] = f32x4{0.f, 0.f, 0.f, 0.f};

  const int mrow = (w & 1) * 64;
  const int ncol = (w >> 1) * 64;

  int4 cidx[4];
#pragma unroll
  for (int jj = 0; jj < 4; ++jj) {
    const int rit = w * 32 + jj * 8 + lrow8;
    cidx[jj].x = tokd[(row0 + rit) * LTOK + 0];
    cidx[jj].y = tokd[(row0 + rit) * LTOK + 1];
    cidx[jj].z = tokd[(row0 + rit) * LTOK + 2];
    cidx[jj].w = 0;
  }

#pragma unroll
  for (int k0 = 0; k0 < KD_EMB; k0 += 64) {
    __syncthreads();
#pragma unroll
    for (int jj = 0; jj < 4; ++jj) {
      const int id = ((const int*)&cidx[jj])[k0 >> 7];
      const u16* base = Ebf + (size_t)id * HD;
      const int rit = w * 32 + jj * 8 + lrow8;
      async16(base + (k0 & 127) + swz * 8, &As[(w * 32 + jj * 8) * 64]);
      async16(Lbf + (size_t)rit * KD_EMB + k0 + swz * 8, &Bs[(w * 32 + jj * 8) * 64]);
    }
    __syncthreads();
#pragma unroll
    for (int ks = 0; ks < 2; ++ks) {
      bf16x8 af[4], bfr[4];
      const int pc = ((ks * 4 + q) ^ (L & 7)) * 8;
#pragma unroll
      for (int mt = 0; mt < 4; ++mt)
        af[mt] = *(const bf16x8*)&As[(mrow + mt * 16 + (L & 15)) * 64 + pc];
#pragma unroll
      for (int nt = 0; nt < 4; ++nt)
        bfr[nt] = *(const bf16x8*)&Bs[(ncol + nt * 16 + (L & 15)) * 64 + pc];
#pragma unroll
      for (int mt = 0; mt < 4; ++mt)
#pragma unroll
        for (int nt = 0; nt < 4; ++nt)
          acc[mt][nt] = __builtin_amdgcn_mfma_f32_16x16x32_bf16(af[mt], bfr[nt], acc[mt][nt], 0, 0, 0);
    }
  }

#pragma unroll
  for (int nt = 0; nt < 4; ++nt) {
    const int col = ncol + nt * 16 + (L & 15);
    const float bb = bias[col];
#pragma unroll
    for (int mt = 0; mt < 4; ++mt) {
#pragma unroll
      for (int i = 0; i < 4; ++i) {
        const int row = row0 + mrow + mt * 16 + q * 4 + i;
        const float v = acc[mt][nt][i] + bb;
        outf[(size_t)row * NC_EMB + col] = v;
        outb[(size_t)row * NC_EMB + col] = f2bf(v);
      }
    }
  }
}

// ---------------------------------------------------------------------------
// LSTM cell: f = sum_k sig(pre_fk)*c_k ; gates ; c (f32), h (bf16),
// t += h (f32) and bf16 shadow tbf.
// ---------------------------------------------------------------------------
__global__ __launch_bounds__(256) void cell_k(
    const u16* __restrict__ pre, const int* __restrict__ idxs,
    const float* __restrict__ c_prev, float* __restrict__ c_cur,
    u16* __restrict__ h_cur, float* __restrict__ t_io, u16* __restrict__ tbf)
{
  const int g = blockIdx.x * 256 + threadIdx.x;
  const int r = g >> 7;
  const int j = g & 127;
  const u16* pr = pre + (size_t)r * NC_STEP;
  float f = 0.f;
#pragma unroll
  for (int k = 0; k < KCH; ++k) {
    const int id = idxs[r * KCH + k];
    const float cg = (id >= 1) ? c_prev[(size_t)(id - 1) * HD + j] : 0.f;
    f += sigm(bf2f(pr[k * HD + j])) * cg;
  }
  const float iv = sigm(bf2f(pr[4 * HD + j]));
  const float uv = tanh_fast(bf2f(pr[5 * HD + j]));
  const float ov = sigm(bf2f(pr[6 * HD + j]));
  const float cn = iv * uv + f;
  const float hv = ov * tanh_fast(cn);
  c_cur[g] = cn;
  h_cur[g] = f2bf(hv);
  const float tn = t_io[g] + hv;
  t_io[g] = tn;
  tbf[g] = f2bf(tn);
}

__global__ __launch_bounds__(256) void conv_k(const float* __restrict__ src,
                                              u16* __restrict__ dst, int n4)
{
  const int g = blockIdx.x * 256 + threadIdx.x;
  if (g < n4) {
    float4 v = ((const float4*)src)[g];
    ((ushort4*)dst)[g] = make_ushort4(f2bf(v.x), f2bf(v.y), f2bf(v.z), f2bf(v.w));
  }
}

// Build U_big[l][896][640] (bf16) = [Uf;Uiuo | W_w(mapped)] + fused f32 biases.
__global__ __launch_bounds__(256) void prep_k(
    const float* __restrict__ Uf_w, const float* __restrict__ Uf_b,
    const float* __restrict__ Uiuo_w, const float* __restrict__ Uiuo_b,
    const float* __restrict__ W_w, const float* __restrict__ W_b,
    u16* __restrict__ Ubig, float* __restrict__ biasbig)
{
  const int l = blockIdx.y;
  const int e = blockIdx.x * 256 + threadIdx.x;
  const int c = e / KD_STEP;
  const int k = e % KD_STEP;
  float v;
  if (k < 512) {
    v = (c < 512) ? Uf_w[((size_t)l * 512 + c) * 512 + k]
                  : Uiuo_w[((size_t)l * 384 + (c - 512)) * 512 + k];
  } else {
    const int q = k - 512;
    const int wr = (c < 512) ? (c & 127) : (128 + (c - 512));
    v = W_w[((size_t)l * 512 + wr) * 128 + q];
  }
  Ubig[((size_t)l * 896 + c) * 640 + k] = f2bf(v);
  if (e < 896) {
    const float b = (e < 512)
        ? (Uf_b[l * 512 + e] + W_b[l * 512 + (e & 127)])
        : (Uiuo_b[l * 384 + (e - 512)] + W_b[l * 512 + 128 + (e - 512)]);
    biasbig[l * 896 + e] = b;
  }
}

// Output (FLOAT32): hx = tile(t_final,2), cx = tile(c_final,2).
__global__ __launch_bounds__(256) void fin_k(
    const float* __restrict__ t_fin, const float* __restrict__ c_fin,
    float* __restrict__ out)
{
  const size_t NH = (size_t)NNODE * HD;
  const size_t g = (size_t)blockIdx.x * 256 + threadIdx.x;
  const float h = t_fin[g];
  const float c = c_fin[g];
  out[g] = h;
  out[NH + g] = h;
  out[2 * NH + g] = c;
  out[3 * NH + g] = c;
}

extern "C" void kernel_launch(void* const* d_in, const int* in_sizes, int n_in,
                              void* d_out, int out_size, void* d_ws, size_t ws_size,
                              hipStream_t stream)
{
  (void)in_sizes; (void)n_in; (void)out_size; (void)ws_size;
  const int*   tokens  = (const int*)d_in[0];
  const int*   indices = (const int*)d_in[1];
  const float* E       = (const float*)d_in[2];
  const float* lin_w   = (const float*)d_in[3];
  const float* lin_b   = (const float*)d_in[4];
  const float* Uf_w    = (const float*)d_in[5];
  const float* Uf_b    = (const float*)d_in[6];
  const float* Uiuo_w  = (const float*)d_in[7];
  const float* Uiuo_b  = (const float*)d_in[8];
  const float* W_w     = (const float*)d_in[9];
  const float* W_b     = (const float*)d_in[10];
  float* out = (float*)d_out;   // FLOAT32 output (R8-proven)

  const size_t NH = (size_t)NNODE * HD;

  char* ws = (char*)d_ws;
  size_t off = 0;
  auto alloc = [&](size_t bytes) -> void* {
    void* p = ws + off;
    off = (off + bytes + 255) & ~(size_t)255;
    return p;
  };
  u16*   Ubig    = (u16*)alloc((size_t)2 * 896 * 640 * 2);
  float* biasbig = (float*)alloc(2 * 896 * 4);
  u16*   Ebf     = (u16*)alloc((size_t)50000 * HD * 2);
  u16*   Lbf     = (u16*)alloc((size_t)HD * KD_EMB * 2);
  float* tslice  = (float*)alloc(NH * 4);
  u16*   tbf     = (u16*)alloc(NH * 2);
  u16*   h0a     = (u16*)alloc(NH * 2);
  u16*   h0b     = (u16*)alloc(NH * 2);
  u16*   h1a     = (u16*)alloc(NH * 2);
  u16*   h1b     = (u16*)alloc(NH * 2);
  float* c0a     = (float*)alloc(NH * 4);
  float* c0b     = (float*)alloc(NH * 4);
  float* c1a     = (float*)alloc(NH * 4);
  float* c1b     = (float*)alloc(NH * 4);
  u16*   pre     = (u16*)alloc((size_t)NNODE * NC_STEP * 2);
  u16*   zbuf    = (u16*)alloc(512);

  u16*   h0[2] = {h0a, h0b};
  u16*   h1[2] = {h1a, h1b};
  float* c0[2] = {c0a, c0b};
  float* c1[2] = {c1a, c1b};

  hipMemsetAsync(zbuf, 0, 512, stream);
  hipMemsetAsync(h0[0], 0, NH * 2, stream);
  hipMemsetAsync(h1[0], 0, NH * 2, stream);
  hipMemsetAsync(c0[0], 0, NH * 4, stream);
  hipMemsetAsync(c1[0], 0, NH * 4, stream);
  prep_k<<<dim3(2240, 2), 256, 0, stream>>>(Uf_w, Uf_b, Uiuo_w, Uiuo_b, W_w, W_b,
                                            Ubig, biasbig);
  conv_k<<<dim3((50000 * HD / 4 + 255) / 256), 256, 0, stream>>>(E, Ebf, 50000 * HD / 4);
  conv_k<<<dim3((HD * KD_EMB / 4 + 255) / 256), 256, 0, stream>>>(lin_w, Lbf, HD * KD_EMB / 4);

  for (int d = 0; d < DD; ++d) {
    const int ri = d & 1, wi = (d + 1) & 1;
    const int* idxd = indices + (size_t)d * NNODE * KCH;
    const int* tokd = tokens + (size_t)d * NNODE * LTOK;

    // tslice (f32) + tbf (bf16) = gather(Ebf, tokens[d]) @ Lbf^T + lin_b
    gemm_emb_k<<<dim3(NNODE / 128), 256, 0, stream>>>(
        Ebf, tokd, Lbf, lin_b, tslice, tbf);

    for (int l = 0; l < 2; ++l) {
      const u16*   hp = (l == 0) ? h0[ri] : h1[ri];
      u16*         hc = (l == 0) ? h0[wi] : h1[wi];
      const float* cp = (l == 0) ? c0[ri] : c1[ri];
      float*       cc = (l == 0) ? c0[wi] : c1[wi];
      const u16* Ul = Ubig + (size_t)l * 896 * 640;
      const float* bl = biasbig + l * 896;
      gemm8_k<<<dim3((NNODE / BM) * (NC_STEP / BN)), 256, 0, stream>>>(
          hp, tbf, idxd, Ul, bl, pre, zbuf);
      cell_k<<<dim3((int)(NH / 256)), 256, 0, stream>>>(
          pre, idxd, cp, cc, hc, tslice, tbf);
    }
  }
  // after d=11: tslice = t_final, c1[0] = c_final
  fin_k<<<dim3((int)(NH / 256)), 256, 0, stream>>>(tslice, c1[0], out);
}

// Round 10
// 2102.691 us; speedup vs baseline: 1.0895x; 1.0895x over previous
//
#include <hip/hip_runtime.h>
#include <cstdint>
#include <cstddef>

#define DD 12
#define NNODE 32768
#define LTOK 3
#define KCH 4
#define HD 128
#define NC_STEP 896
#define KD_STEP 640
#define NC_EMB 128
#define KD_EMB 384

typedef unsigned short u16;
typedef __attribute__((ext_vector_type(8))) __bf16 bf16x8;
typedef __attribute__((ext_vector_type(4))) float f32x4;

__device__ __forceinline__ float bf2f(unsigned int u) {
  union { unsigned int i; float f; } v; v.i = (u & 0xffffu) << 16; return v.f;
}
__device__ __forceinline__ u16 f2bf(float f) {
  union { float f; unsigned int i; } v; v.f = f;
  unsigned int x = v.i;
  return (u16)((x + 0x7fffu + ((x >> 16) & 1u)) >> 16);
}
__device__ __forceinline__ float sigm(float x) { return 1.f / (1.f + __expf(-x)); }
__device__ __forceinline__ float tanh_fast(float x) { return 1.f - 2.f / (1.f + __expf(2.f * x)); }
__device__ __forceinline__ void async16(const void* g, void* l) {
  __builtin_amdgcn_global_load_lds((const __attribute__((address_space(1))) unsigned int*)g,
                                   (__attribute__((address_space(3))) unsigned int*)l, 16, 0, 0);
}

// ---------------------------------------------------------------------------
// R18 step GEMM = R8 VERBATIM (53.4 us, best measured; R9's BM=128 regressed:
// fewer waves/CU + doubled per-block overhead). pre = A[32768,640] @
// Ubig[896,640]^T + bias.
// BM=256 x BN=128, BK=32, 512 thr / 8 waves (4M x 2N -> per-wave 64x64).
// 3-buffer LDS 72 KB -> 2 blocks/CU. Per K-tile: stage(t+2) issue-early
// (3 async16/wave), 8 ds_read_b128, 16 MFMA w/ setprio, belt vmcnt(3)
// (leaves S(t+2) in flight, never drain-to-0 mid-loop), ONE raw s_barrier.
// Swizzle (R8-verified, 0 conflicts): 64B rows, phys 16B slot s of row r
// holds global chunk s ^ ((r>>1)&3).
//   stage: lane L -> row L>>2, slot L&3 -> global chunk (L&3)^((L>>3)&3)
//   read:  chunk q at row (..+(L&15)) -> phys slot q ^ ((L>>1)&3)
// Grid: 896 = 8*112 bijective XCD chunks, col-tile fastest (A-panel L2
// reuse: FETCH 88.8 -> 29 MB).
// ---------------------------------------------------------------------------
#define BM 256
#define BN 128
#define BK 32

__global__ __launch_bounds__(512, 4) void gemm8_k(
    const u16* __restrict__ Abf, const u16* __restrict__ Tbf,
    const int* __restrict__ gidx, const u16* __restrict__ B,
    const float* __restrict__ bias, u16* __restrict__ outb,
    const u16* __restrict__ zbuf)
{
  __shared__ u16 As[3][BM * BK];   // 3 x 16 KB
  __shared__ u16 Bs[3][BN * BK];   // 3 x 8 KB
  const int t = threadIdx.x;
  const int w = t >> 6;            // 0..7
  const int L = t & 63;
  const int q = L >> 4;            // 0..3 : k-chunk this lane's MFMA frag uses
  const int r16 = L >> 2;          // 0..15 : row within 16-row stage slab
  const int sub = L & 3;           // 16B landing slot within 64B row
  const int swz = sub ^ ((L >> 3) & 3);   // global chunk this lane fetches

  // bijective chunked XCD swizzle: 896 = 8 * 112; col-tile fastest in chunk
  const int bid = blockIdx.x;
  const int wg = (bid & 7) * 112 + (bid >> 3);
  const int rt = wg / 7;
  const int ct = wg - rt * 7;
  const int row0 = rt * BM;
  const int col0 = ct * BN;

  const int wm = w >> 1;           // 0..3 : 64-row group
  const int wn = w & 1;            // 0..1 : 64-col group
  const int mrow = wm * 64;
  const int ncol = wn * 64;

  f32x4 acc[4][4];
#pragma unroll
  for (int a = 0; a < 4; ++a)
#pragma unroll
    for (int b = 0; b < 4; ++b)
      acc[a][b] = f32x4{0.f, 0.f, 0.f, 0.f};

  // gather indices: wave stages A rows w*32 + j*16 + r16, j=0,1
  int4 cidx[2];
#pragma unroll
  for (int j = 0; j < 2; ++j)
    cidx[j] = *(const int4*)&gidx[(row0 + w * 32 + j * 16 + r16) * KCH];

  // stage k-chunk [k0,k0+32) of tile into buffer sel: 2 A instrs + 1 B instr
  auto stageAll = [&](const int k0, const int sel) {
#pragma unroll
    for (int j = 0; j < 2; ++j) {
      const int rbase = w * 32 + j * 16;     // 16-row slab
      const u16* src;
      if (k0 < 4 * HD) {
        const int id = ((const int*)&cidx[j])[k0 >> 7];
        const u16* base = (id >= 1) ? (Abf + (size_t)(id - 1) * HD) : zbuf;
        src = base + (k0 & 127) + swz * 8;
      } else {
        src = Tbf + (size_t)(row0 + rbase + r16) * HD + (k0 - 4 * HD) + swz * 8;
      }
      async16(src, &As[sel][rbase * BK]);
    }
    const int rb = w * 16;                    // B: 16 rows per wave
    async16(B + (size_t)(col0 + rb + r16) * KD_STEP + k0 + swz * 8,
            &Bs[sel][rb * BK]);
  };

  // prologue: stage tiles 0,1 (6 instrs); wait tile 0 only
  stageAll(0, 0);
  stageAll(32, 1);
  asm volatile("s_waitcnt vmcnt(3)" ::: "memory");
  __builtin_amdgcn_sched_barrier(0);
  __builtin_amdgcn_s_barrier();
  __builtin_amdgcn_sched_barrier(0);

  constexpr int NT = KD_STEP / BK;   // 20
#pragma unroll
  for (int tt = 0; tt < NT; ++tt) {
    const int rd = tt % 3;
    // issue-early: tile t+2 staging (its buffer's readers done at barrier t-1)
    if (tt + 2 < NT) stageAll((tt + 2) * BK, (tt + 2) % 3);

    // fragment reads: phys slot = q ^ ((row>>1)&3), row bits from L&15
    const int pc = (q ^ ((L >> 1) & 3)) * 8;
    bf16x8 af[4], bfv[4];
#pragma unroll
    for (int mt = 0; mt < 4; ++mt)
      af[mt] = *(const bf16x8*)&As[rd][(mrow + mt * 16 + (L & 15)) * BK + pc];
#pragma unroll
    for (int nt = 0; nt < 4; ++nt)
      bfv[nt] = *(const bf16x8*)&Bs[rd][(ncol + nt * 16 + (L & 15)) * BK + pc];

    __builtin_amdgcn_s_setprio(1);
#pragma unroll
    for (int mt = 0; mt < 4; ++mt)
#pragma unroll
      for (int nt = 0; nt < 4; ++nt)
        acc[mt][nt] = __builtin_amdgcn_mfma_f32_16x16x32_bf16(
            af[mt], bfv[nt], acc[mt][nt], 0, 0, 0);
    __builtin_amdgcn_s_setprio(0);

    // tile-end sync: counted vmcnt (leaves S(t+2) in flight) + ONE barrier
    if (tt < NT - 1) {
      if (tt + 2 < NT) asm volatile("s_waitcnt vmcnt(3)" ::: "memory");
      else             asm volatile("s_waitcnt vmcnt(0)" ::: "memory");
      __builtin_amdgcn_sched_barrier(0);
      __builtin_amdgcn_s_barrier();
      __builtin_amdgcn_sched_barrier(0);
    }
  }

  // epilogue: C/D layout col=lane&15, row=(lane>>4)*4+i
#pragma unroll
  for (int nt = 0; nt < 4; ++nt) {
    const int col = col0 + ncol + nt * 16 + (L & 15);
    const float bb = bias[col];
#pragma unroll
    for (int mt = 0; mt < 4; ++mt) {
#pragma unroll
      for (int i = 0; i < 4; ++i) {
        const int row = row0 + mrow + mt * 16 + q * 4 + i;
        outb[(size_t)row * NC_STEP + col] = f2bf(acc[mt][nt][i] + bb);
      }
    }
  }
}

// ---------------------------------------------------------------------------
// R18 embed GEMM: PORTED to the R8 rhythm (was the last full-drain 2-barrier
// kernel, ~17 us). tslice[f32] & tbf[bf16] = gather(Ebf,tokens) @ Lbf^T + b.
// BM=64 x BN=128, BK=32, 256 thr / 4 waves (2M x 2N -> per-wave 32x64).
// 3 buffers x (A 4KB + B 8KB) = 36 KB -> 4 blocks/CU. Grid 512 blocks.
// Per K-tile per wave: 3 async16 stage (1 A slab + 2 B slabs, tile t+2),
// 6 ds_read_b128, 8 MFMA w/ setprio, belt vmcnt(3), ONE s_barrier.
// Ledger identical to step: S(t+1) issued at t-1, drained by end-of-t
// vmcnt(3) (FIFO leaves the 3 just-issued S(t+2)); WAR via barrier t-1.
// Swizzle identical (verified 0-conflict). NT = 384/32 = 12; A token
// index = k0>>7 (tiles 0-3 -> tok0, 4-7 -> tok1, 8-11 -> tok2).
// ---------------------------------------------------------------------------
__global__ __launch_bounds__(256, 4) void gemm_emb_k(
    const u16* __restrict__ Ebf, const int* __restrict__ tokd,
    const u16* __restrict__ Lbf, const float* __restrict__ bias,
    float* __restrict__ outf, u16* __restrict__ outb)
{
  __shared__ u16 As[3][64 * BK];    // 3 x 4 KB
  __shared__ u16 Bs[3][128 * BK];   // 3 x 8 KB
  const int t = threadIdx.x;
  const int w = t >> 6;            // 0..3
  const int L = t & 63;
  const int q = L >> 4;
  const int r16 = L >> 2;
  const int sub = L & 3;
  const int swz = sub ^ ((L >> 3) & 3);
  const int row0 = blockIdx.x * 64;

  const int wm = w >> 1;           // 0..1 : 32-row group
  const int wn = w & 1;            // 0..1 : 64-col group
  const int mrow = wm * 32;
  const int ncol = wn * 64;

  f32x4 acc[2][4];
#pragma unroll
  for (int a = 0; a < 2; ++a)
#pragma unroll
    for (int b = 0; b < 4; ++b)
      acc[a][b] = f32x4{0.f, 0.f, 0.f, 0.f};

  // token indices for this lane's A stage row (row0 + w*16 + r16)
  const int arow = row0 + w * 16 + r16;
  int tok[3];
#pragma unroll
  for (int j = 0; j < 3; ++j)
    tok[j] = tokd[arow * LTOK + j];

  // stage k-chunk [k0,k0+32): 1 A slab (16 rows) + 2 B slabs per wave
  auto stageAll = [&](const int k0, const int sel) {
    const int id = tok[k0 >> 7];
    async16(Ebf + (size_t)id * HD + (k0 & 127) + swz * 8,
            &As[sel][(w * 16) * BK]);
#pragma unroll
    for (int j = 0; j < 2; ++j) {
      const int rb = w * 32 + j * 16;        // B: 32 rows per wave
      async16(Lbf + (size_t)(rb + r16) * KD_EMB + k0 + swz * 8,
              &Bs[sel][rb * BK]);
    }
  };

  // prologue: stage tiles 0,1; wait tile 0 only
  stageAll(0, 0);
  stageAll(32, 1);
  asm volatile("s_waitcnt vmcnt(3)" ::: "memory");
  __builtin_amdgcn_sched_barrier(0);
  __builtin_amdgcn_s_barrier();
  __builtin_amdgcn_sched_barrier(0);

  constexpr int NT = KD_EMB / BK;   // 12
#pragma unroll
  for (int tt = 0; tt < NT; ++tt) {
    const int rd = tt % 3;
    if (tt + 2 < NT) stageAll((tt + 2) * BK, (tt + 2) % 3);

    const int pc = (q ^ ((L >> 1) & 3)) * 8;
    bf16x8 af[2], bfv[4];
#pragma unroll
    for (int mt = 0; mt < 2; ++mt)
      af[mt] = *(const bf16x8*)&As[rd][(mrow + mt * 16 + (L & 15)) * BK + pc];
#pragma unroll
    for (int nt = 0; nt < 4; ++nt)
      bfv[nt] = *(const bf16x8*)&Bs[rd][(ncol + nt * 16 + (L & 15)) * BK + pc];

    __builtin_amdgcn_s_setprio(1);
#pragma unroll
    for (int mt = 0; mt < 2; ++mt)
#pragma unroll
      for (int nt = 0; nt < 4; ++nt)
        acc[mt][nt] = __builtin_amdgcn_mfma_f32_16x16x32_bf16(
            af[mt], bfv[nt], acc[mt][nt], 0, 0, 0);
    __builtin_amdgcn_s_setprio(0);

    if (tt < NT - 1) {
      if (tt + 2 < NT) asm volatile("s_waitcnt vmcnt(3)" ::: "memory");
      else             asm volatile("s_waitcnt vmcnt(0)" ::: "memory");
      __builtin_amdgcn_sched_barrier(0);
      __builtin_amdgcn_s_barrier();
      __builtin_amdgcn_sched_barrier(0);
    }
  }

  // epilogue: col=lane&15, row=(lane>>4)*4+i ; write f32 tslice + bf16 tbf
#pragma unroll
  for (int nt = 0; nt < 4; ++nt) {
    const int col = ncol + nt * 16 + (L & 15);
    const float bb = bias[col];
#pragma unroll
    for (int mt = 0; mt < 2; ++mt) {
#pragma unroll
      for (int i = 0; i < 4; ++i) {
        const int row = row0 + mrow + mt * 16 + q * 4 + i;
        const float v = acc[mt][nt][i] + bb;
        outf[(size_t)row * NC_EMB + col] = v;
        outb[(size_t)row * NC_EMB + col] = f2bf(v);
      }
    }
  }
}

// ---------------------------------------------------------------------------
// LSTM cell: f = sum_k sig(pre_fk)*c_k ; gates ; c (f32), h (bf16),
// t += h (f32) and bf16 shadow tbf.
// ---------------------------------------------------------------------------
__global__ __launch_bounds__(256) void cell_k(
    const u16* __restrict__ pre, const int* __restrict__ idxs,
    const float* __restrict__ c_prev, float* __restrict__ c_cur,
    u16* __restrict__ h_cur, float* __restrict__ t_io, u16* __restrict__ tbf)
{
  const int g = blockIdx.x * 256 + threadIdx.x;
  const int r = g >> 7;
  const int j = g & 127;
  const u16* pr = pre + (size_t)r * NC_STEP;
  float f = 0.f;
#pragma unroll
  for (int k = 0; k < KCH; ++k) {
    const int id = idxs[r * KCH + k];
    const float cg = (id >= 1) ? c_prev[(size_t)(id - 1) * HD + j] : 0.f;
    f += sigm(bf2f(pr[k * HD + j])) * cg;
  }
  const float iv = sigm(bf2f(pr[4 * HD + j]));
  const float uv = tanh_fast(bf2f(pr[5 * HD + j]));
  const float ov = sigm(bf2f(pr[6 * HD + j]));
  const float cn = iv * uv + f;
  const float hv = ov * tanh_fast(cn);
  c_cur[g] = cn;
  h_cur[g] = f2bf(hv);
  const float tn = t_io[g] + hv;
  t_io[g] = tn;
  tbf[g] = f2bf(tn);
}

__global__ __launch_bounds__(256) void conv_k(const float* __restrict__ src,
                                              u16* __restrict__ dst, int n4)
{
  const int g = blockIdx.x * 256 + threadIdx.x;
  if (g < n4) {
    float4 v = ((const float4*)src)[g];
    ((ushort4*)dst)[g] = make_ushort4(f2bf(v.x), f2bf(v.y), f2bf(v.z), f2bf(v.w));
  }
}

// Build U_big[l][896][640] (bf16) = [Uf;Uiuo | W_w(mapped)] + fused f32 biases.
__global__ __launch_bounds__(256) void prep_k(
    const float* __restrict__ Uf_w, const float* __restrict__ Uf_b,
    const float* __restrict__ Uiuo_w, const float* __restrict__ Uiuo_b,
    const float* __restrict__ W_w, const float* __restrict__ W_b,
    u16* __restrict__ Ubig, float* __restrict__ biasbig)
{
  const int l = blockIdx.y;
  const int e = blockIdx.x * 256 + threadIdx.x;
  const int c = e / KD_STEP;
  const int k = e % KD_STEP;
  float v;
  if (k < 512) {
    v = (c < 512) ? Uf_w[((size_t)l * 512 + c) * 512 + k]
                  : Uiuo_w[((size_t)l * 384 + (c - 512)) * 512 + k];
  } else {
    const int q = k - 512;
    const int wr = (c < 512) ? (c & 127) : (128 + (c - 512));
    v = W_w[((size_t)l * 512 + wr) * 128 + q];
  }
  Ubig[((size_t)l * 896 + c) * 640 + k] = f2bf(v);
  if (e < 896) {
    const float b = (e < 512)
        ? (Uf_b[l * 512 + e] + W_b[l * 512 + (e & 127)])
        : (Uiuo_b[l * 384 + (e - 512)] + W_b[l * 512 + 128 + (e - 512)]);
    biasbig[l * 896 + e] = b;
  }
}

// Output (FLOAT32): hx = tile(t_final,2), cx = tile(c_final,2).
__global__ __launch_bounds__(256) void fin_k(
    const float* __restrict__ t_fin, const float* __restrict__ c_fin,
    float* __restrict__ out)
{
  const size_t NH = (size_t)NNODE * HD;
  const size_t g = (size_t)blockIdx.x * 256 + threadIdx.x;
  const float h = t_fin[g];
  const float c = c_fin[g];
  out[g] = h;
  out[NH + g] = h;
  out[2 * NH + g] = c;
  out[3 * NH + g] = c;
}

extern "C" void kernel_launch(void* const* d_in, const int* in_sizes, int n_in,
                              void* d_out, int out_size, void* d_ws, size_t ws_size,
                              hipStream_t stream)
{
  (void)in_sizes; (void)n_in; (void)out_size; (void)ws_size;
  const int*   tokens  = (const int*)d_in[0];
  const int*   indices = (const int*)d_in[1];
  const float* E       = (const float*)d_in[2];
  const float* lin_w   = (const float*)d_in[3];
  const float* lin_b   = (const float*)d_in[4];
  const float* Uf_w    = (const float*)d_in[5];
  const float* Uf_b    = (const float*)d_in[6];
  const float* Uiuo_w  = (const float*)d_in[7];
  const float* Uiuo_b  = (const float*)d_in[8];
  const float* W_w     = (const float*)d_in[9];
  const float* W_b     = (const float*)d_in[10];
  float* out = (float*)d_out;   // FLOAT32 output (R8-proven)

  const size_t NH = (size_t)NNODE * HD;

  char* ws = (char*)d_ws;
  size_t off = 0;
  auto alloc = [&](size_t bytes) -> void* {
    void* p = ws + off;
    off = (off + bytes + 255) & ~(size_t)255;
    return p;
  };
  u16*   Ubig    = (u16*)alloc((size_t)2 * 896 * 640 * 2);
  float* biasbig = (float*)alloc(2 * 896 * 4);
  u16*   Ebf     = (u16*)alloc((size_t)50000 * HD * 2);
  u16*   Lbf     = (u16*)alloc((size_t)HD * KD_EMB * 2);
  float* tslice  = (float*)alloc(NH * 4);
  u16*   tbf     = (u16*)alloc(NH * 2);
  u16*   h0a     = (u16*)alloc(NH * 2);
  u16*   h0b     = (u16*)alloc(NH * 2);
  u16*   h1a     = (u16*)alloc(NH * 2);
  u16*   h1b     = (u16*)alloc(NH * 2);
  float* c0a     = (float*)alloc(NH * 4);
  float* c0b     = (float*)alloc(NH * 4);
  float* c1a     = (float*)alloc(NH * 4);
  float* c1b     = (float*)alloc(NH * 4);
  u16*   pre     = (u16*)alloc((size_t)NNODE * NC_STEP * 2);
  u16*   zbuf    = (u16*)alloc(512);

  u16*   h0[2] = {h0a, h0b};
  u16*   h1[2] = {h1a, h1b};
  float* c0[2] = {c0a, c0b};
  float* c1[2] = {c1a, c1b};

  hipMemsetAsync(zbuf, 0, 512, stream);
  hipMemsetAsync(h0[0], 0, NH * 2, stream);
  hipMemsetAsync(h1[0], 0, NH * 2, stream);
  hipMemsetAsync(c0[0], 0, NH * 4, stream);
  hipMemsetAsync(c1[0], 0, NH * 4, stream);
  prep_k<<<dim3(2240, 2), 256, 0, stream>>>(Uf_w, Uf_b, Uiuo_w, Uiuo_b, W_w, W_b,
                                            Ubig, biasbig);
  conv_k<<<dim3((50000 * HD / 4 + 255) / 256), 256, 0, stream>>>(E, Ebf, 50000 * HD / 4);
  conv_k<<<dim3((HD * KD_EMB / 4 + 255) / 256), 256, 0, stream>>>(lin_w, Lbf, HD * KD_EMB / 4);

  for (int d = 0; d < DD; ++d) {
    const int ri = d & 1, wi = (d + 1) & 1;
    const int* idxd = indices + (size_t)d * NNODE * KCH;
    const int* tokd = tokens + (size_t)d * NNODE * LTOK;

    // tslice (f32) + tbf (bf16) = gather(Ebf, tokens[d]) @ Lbf^T + lin_b
    gemm_emb_k<<<dim3(NNODE / 64), 256, 0, stream>>>(
        Ebf, tokd, Lbf, lin_b, tslice, tbf);

    for (int l = 0; l < 2; ++l) {
      const u16*   hp = (l == 0) ? h0[ri] : h1[ri];
      u16*         hc = (l == 0) ? h0[wi] : h1[wi];
      const float* cp = (l == 0) ? c0[ri] : c1[ri];
      float*       cc = (l == 0) ? c0[wi] : c1[wi];
      const u16* Ul = Ubig + (size_t)l * 896 * 640;
      const float* bl = biasbig + l * 896;
      gemm8_k<<<dim3((NNODE / BM) * (NC_STEP / BN)), 512, 0, stream>>>(
          hp, tbf, idxd, Ul, bl, pre, zbuf);
      cell_k<<<dim3((int)(NH / 256)), 256, 0, stream>>>(
          pre, idxd, cp, cc, hc, tslice, tbf);
    }
  }
  // after d=11: tslice = t_final, c1[0] = c_final
  fin_k<<<dim3((int)(NH / 256)), 256, 0, stream>>>(tslice, c1[0], out);
}

// Round 11
// 1909.330 us; speedup vs baseline: 1.1998x; 1.1013x over previous
//
#include <hip/hip_runtime.h>
#include <cstdint>
#include <cstddef>

#define DD 12
#define NNODE 32768
#define LTOK 3
#define KCH 4
#define HD 128
#define KD_STEP 640
#define NC_EMB 128
#define KD_EMB 384
#define NCP 1024   // padded gate-interleaved cols: c' = j*8+g, g in [0,8)

typedef unsigned short u16;
typedef __attribute__((ext_vector_type(8))) __bf16 bf16x8;
typedef __attribute__((ext_vector_type(4))) float f32x4;

__device__ __forceinline__ float bf2f(unsigned int u) {
  union { unsigned int i; float f; } v; v.i = (u & 0xffffu) << 16; return v.f;
}
__device__ __forceinline__ u16 f2bf(float f) {
  union { float f; unsigned int i; } v; v.f = f;
  unsigned int x = v.i;
  return (u16)((x + 0x7fffu + ((x >> 16) & 1u)) >> 16);
}
__device__ __forceinline__ float sigm(float x) { return 1.f / (1.f + __expf(-x)); }
__device__ __forceinline__ float tanh_fast(float x) { return 1.f - 2.f / (1.f + __expf(2.f * x)); }
__device__ __forceinline__ void async16(const void* g, void* l) {
  __builtin_amdgcn_global_load_lds((const __attribute__((address_space(1))) unsigned int*)g,
                                   (__attribute__((address_space(3))) unsigned int*)l, 16, 0, 0);
}

// ---------------------------------------------------------------------------
// R19 FUSED step GEMM + LSTM cell. Eliminates the pre round-trip (58.7 MB
// write + 58.7 MB read per layer-step) and 24 cell_k launches.
// Ubig is GATE-INTERLEAVED by prep_k: row c' = j*8+g (g=0..3 f-gates,
// 4=i, 5=u, 6=o, 7=zero pad; 1024 rows/layer). A BN=128 tile therefore
// holds 16 complete j's x 8 gates -> the cell is computable per block.
// Loop = R8 verbatim (53.4 us proven): BM=256/BN=128/BK=32, 512 thr/8 waves
// (4Mx2N, 64x64/wave), 3-buffer LDS 72 KB (2 blocks/CU), stage(t+2)
// issue-early, belt vmcnt(3) never-drain-to-0, ONE raw s_barrier/tile,
// R8-verified swizzle (0 conflicts).
// Epilogue: stage f2bf(acc+bias) into the dead 72 KB LDS as [256][128]
// bf16 (write 2-way free; read b128 = 8 gates, conflict-free: lanes 0-7
// read j*16B -> all 32 banks), __syncthreads, then 8 cells/thread:
// 16 lanes share a row -> ids broadcast, c_prev/t accesses are 64 B
// coalesced segments. t/tbf ping-pong (t_in/t_out) because the 8 col-tile
// blocks of a row-panel race on t otherwise.
// Rounding parity with R10: pre was f2bf'd before cell there; here the LDS
// staging applies the same f2bf. h/tbf/c identical arithmetic.
// Grid: 128 row x 8 col = 1024 = 8*128 bijective XCD chunks (2 exact
// CU-rounds), col-tile fastest (A-panel L2 reuse).
// ---------------------------------------------------------------------------
#define BM 256
#define BN 128
#define BK 32
#define ASZ (BM * BK)
#define BSZ (BN * BK)

__global__ __launch_bounds__(512, 4) void gemm_fused_k(
    const u16* __restrict__ Abf, const u16* __restrict__ Tbf,
    const int* __restrict__ gidx, const u16* __restrict__ B,
    const float* __restrict__ bias, const float* __restrict__ c_prev,
    float* __restrict__ c_cur, u16* __restrict__ h_cur,
    const float* __restrict__ t_in, float* __restrict__ t_out,
    u16* __restrict__ tbf_out, const u16* __restrict__ zbuf)
{
  __shared__ u16 smem[3 * ASZ + 3 * BSZ];   // 72 KB; reused by epilogue
  const int tid = threadIdx.x;
  const int w = tid >> 6;          // 0..7
  const int L = tid & 63;
  const int q = L >> 4;
  const int r16 = L >> 2;          // row within 16-row stage slab
  const int swz = (L & 3) ^ ((L >> 3) & 3);   // R8-verified stage swizzle

  // bijective chunked XCD swizzle: 1024 = 8 * 128; col-tile fastest
  const int bid = blockIdx.x;
  const int wg = (bid & 7) * 128 + (bid >> 3);
  const int rt = wg >> 3;          // 0..127
  const int ct = wg & 7;           // 0..7
  const int row0 = rt * BM;
  const int col0 = ct * BN;

  const int wm = w >> 1;           // 0..3 : 64-row group
  const int wn = w & 1;            // 0..1 : 64-col group
  const int mrow = wm * 64;
  const int ncol = wn * 64;

  f32x4 acc[4][4];
#pragma unroll
  for (int a = 0; a < 4; ++a)
#pragma unroll
    for (int b = 0; b < 4; ++b)
      acc[a][b] = f32x4{0.f, 0.f, 0.f, 0.f};

  // gather indices for staging rows w*32 + j*16 + r16
  int4 cidx[2];
#pragma unroll
  for (int j = 0; j < 2; ++j)
    cidx[j] = *(const int4*)&gidx[(row0 + w * 32 + j * 16 + r16) * KCH];

  auto stageAll = [&](const int k0, const int sel) {
#pragma unroll
    for (int j = 0; j < 2; ++j) {
      const int rbase = w * 32 + j * 16;
      const u16* src;
      if (k0 < 4 * HD) {
        const int id = ((const int*)&cidx[j])[k0 >> 7];
        const u16* base = (id >= 1) ? (Abf + (size_t)(id - 1) * HD) : zbuf;
        src = base + (k0 & 127) + swz * 8;
      } else {
        src = Tbf + (size_t)(row0 + rbase + r16) * HD + (k0 - 4 * HD) + swz * 8;
      }
      async16(src, &smem[sel * ASZ + rbase * BK]);
    }
    const int rb = w * 16;
    async16(B + (size_t)(col0 + rb + r16) * KD_STEP + k0 + swz * 8,
            &smem[3 * ASZ + sel * BSZ + rb * BK]);
  };

  // prologue: stage tiles 0,1; wait tile 0 only
  stageAll(0, 0);
  stageAll(32, 1);
  asm volatile("s_waitcnt vmcnt(3)" ::: "memory");
  __builtin_amdgcn_sched_barrier(0);
  __builtin_amdgcn_s_barrier();
  __builtin_amdgcn_sched_barrier(0);

  constexpr int NT = KD_STEP / BK;   // 20
#pragma unroll
  for (int tt = 0; tt < NT; ++tt) {
    const int rd = tt % 3;
    if (tt + 2 < NT) stageAll((tt + 2) * BK, (tt + 2) % 3);

    const int pc = (q ^ ((L >> 1) & 3)) * 8;   // R8-verified read swizzle
    bf16x8 af[4], bfv[4];
#pragma unroll
    for (int mt = 0; mt < 4; ++mt)
      af[mt] = *(const bf16x8*)&smem[rd * ASZ + (mrow + mt * 16 + (L & 15)) * BK + pc];
#pragma unroll
    for (int nt = 0; nt < 4; ++nt)
      bfv[nt] = *(const bf16x8*)&smem[3 * ASZ + rd * BSZ + (ncol + nt * 16 + (L & 15)) * BK + pc];

    __builtin_amdgcn_s_setprio(1);
#pragma unroll
    for (int mt = 0; mt < 4; ++mt)
#pragma unroll
      for (int nt = 0; nt < 4; ++nt)
        acc[mt][nt] = __builtin_amdgcn_mfma_f32_16x16x32_bf16(
            af[mt], bfv[nt], acc[mt][nt], 0, 0, 0);
    __builtin_amdgcn_s_setprio(0);

    if (tt < NT - 1) {
      if (tt + 2 < NT) asm volatile("s_waitcnt vmcnt(3)" ::: "memory");
      else             asm volatile("s_waitcnt vmcnt(0)" ::: "memory");
      __builtin_amdgcn_sched_barrier(0);
      __builtin_amdgcn_s_barrier();
      __builtin_amdgcn_sched_barrier(0);
    }
  }

  // ---- fused epilogue ----
  // all waves past their final-tile LDS reads before we overwrite smem
  __syncthreads();
  // stage pre = f2bf(acc + bias) into smem as [256 rows][128 cols'] bf16
#pragma unroll
  for (int nt = 0; nt < 4; ++nt) {
    const int colL = ncol + nt * 16 + (L & 15);
    const float bb = bias[col0 + colL];
#pragma unroll
    for (int mt = 0; mt < 4; ++mt) {
#pragma unroll
      for (int i = 0; i < 4; ++i) {
        const int rowL = mrow + mt * 16 + q * 4 + i;
        smem[rowL * 128 + colL] = f2bf(acc[mt][nt][i] + bb);
      }
    }
  }
  __syncthreads();
  // 8 complete cells per thread; 16 lanes share a row -> coalesced
  const int jbase = col0 >> 3;     // = ct*16
#pragma unroll
  for (int s = 0; s < 8; ++s) {
    const int o = tid + s * 512;
    const int rowL = o >> 4;
    const int jL = o & 15;
    const int row = row0 + rowL;
    const int jg = jbase + jL;
    const bf16x8 pv = *(const bf16x8*)&smem[rowL * 128 + jL * 8];
    const u16* pu = (const u16*)&pv;
    float p[8];
#pragma unroll
    for (int k = 0; k < 8; ++k) p[k] = bf2f(pu[k]);
    const int4 ids = *(const int4*)&gidx[row * KCH];
    float f = 0.f;
    f += sigm(p[0]) * ((ids.x >= 1) ? c_prev[(size_t)(ids.x - 1) * HD + jg] : 0.f);
    f += sigm(p[1]) * ((ids.y >= 1) ? c_prev[(size_t)(ids.y - 1) * HD + jg] : 0.f);
    f += sigm(p[2]) * ((ids.z >= 1) ? c_prev[(size_t)(ids.z - 1) * HD + jg] : 0.f);
    f += sigm(p[3]) * ((ids.w >= 1) ? c_prev[(size_t)(ids.w - 1) * HD + jg] : 0.f);
    const float cn = sigm(p[4]) * tanh_fast(p[5]) + f;
    const float hv = sigm(p[6]) * tanh_fast(cn);
    const size_t gg = (size_t)row * HD + jg;
    c_cur[gg] = cn;
    h_cur[gg] = f2bf(hv);
    const float tn = t_in[gg] + hv;
    t_out[gg] = tn;
    tbf_out[gg] = f2bf(tn);
  }
}

// ---------------------------------------------------------------------------
// Embed GEMM (R10 rhythm, unchanged): tslice[f32] & tbf[bf16] =
// gather(Ebf,tokens) @ Lbf^T + lin_b. BM=64xBN=128, BK=32, 4 waves,
// 3 buffers 36 KB -> 4 blocks/CU.
// ---------------------------------------------------------------------------
__global__ __launch_bounds__(256, 4) void gemm_emb_k(
    const u16* __restrict__ Ebf, const int* __restrict__ tokd,
    const u16* __restrict__ Lbf, const float* __restrict__ bias,
    float* __restrict__ outf, u16* __restrict__ outb)
{
  __shared__ u16 As[3][64 * BK];    // 3 x 4 KB
  __shared__ u16 Bs[3][128 * BK];   // 3 x 8 KB
  const int t = threadIdx.x;
  const int w = t >> 6;
  const int L = t & 63;
  const int q = L >> 4;
  const int r16 = L >> 2;
  const int swz = (L & 3) ^ ((L >> 3) & 3);
  const int row0 = blockIdx.x * 64;

  const int wm = w >> 1;
  const int wn = w & 1;
  const int mrow = wm * 32;
  const int ncol = wn * 64;

  f32x4 acc[2][4];
#pragma unroll
  for (int a = 0; a < 2; ++a)
#pragma unroll
    for (int b = 0; b < 4; ++b)
      acc[a][b] = f32x4{0.f, 0.f, 0.f, 0.f};

  const int arow = row0 + w * 16 + r16;
  int tok[3];
#pragma unroll
  for (int j = 0; j < 3; ++j)
    tok[j] = tokd[arow * LTOK + j];

  auto stageAll = [&](const int k0, const int sel) {
    const int id = tok[k0 >> 7];
    async16(Ebf + (size_t)id * HD + (k0 & 127) + swz * 8,
            &As[sel][(w * 16) * BK]);
#pragma unroll
    for (int j = 0; j < 2; ++j) {
      const int rb = w * 32 + j * 16;
      async16(Lbf + (size_t)(rb + r16) * KD_EMB + k0 + swz * 8,
              &Bs[sel][rb * BK]);
    }
  };

  stageAll(0, 0);
  stageAll(32, 1);
  asm volatile("s_waitcnt vmcnt(3)" ::: "memory");
  __builtin_amdgcn_sched_barrier(0);
  __builtin_amdgcn_s_barrier();
  __builtin_amdgcn_sched_barrier(0);

  constexpr int NT = KD_EMB / BK;   // 12
#pragma unroll
  for (int tt = 0; tt < NT; ++tt) {
    const int rd = tt % 3;
    if (tt + 2 < NT) stageAll((tt + 2) * BK, (tt + 2) % 3);

    const int pc = (q ^ ((L >> 1) & 3)) * 8;
    bf16x8 af[2], bfv[4];
#pragma unroll
    for (int mt = 0; mt < 2; ++mt)
      af[mt] = *(const bf16x8*)&As[rd][(mrow + mt * 16 + (L & 15)) * BK + pc];
#pragma unroll
    for (int nt = 0; nt < 4; ++nt)
      bfv[nt] = *(const bf16x8*)&Bs[rd][(ncol + nt * 16 + (L & 15)) * BK + pc];

    __builtin_amdgcn_s_setprio(1);
#pragma unroll
    for (int mt = 0; mt < 2; ++mt)
#pragma unroll
      for (int nt = 0; nt < 4; ++nt)
        acc[mt][nt] = __builtin_amdgcn_mfma_f32_16x16x32_bf16(
            af[mt], bfv[nt], acc[mt][nt], 0, 0, 0);
    __builtin_amdgcn_s_setprio(0);

    if (tt < NT - 1) {
      if (tt + 2 < NT) asm volatile("s_waitcnt vmcnt(3)" ::: "memory");
      else             asm volatile("s_waitcnt vmcnt(0)" ::: "memory");
      __builtin_amdgcn_sched_barrier(0);
      __builtin_amdgcn_s_barrier();
      __builtin_amdgcn_sched_barrier(0);
    }
  }

#pragma unroll
  for (int nt = 0; nt < 4; ++nt) {
    const int col = ncol + nt * 16 + (L & 15);
    const float bb = bias[col];
#pragma unroll
    for (int mt = 0; mt < 2; ++mt) {
#pragma unroll
      for (int i = 0; i < 4; ++i) {
        const int row = row0 + mrow + mt * 16 + q * 4 + i;
        const float v = acc[mt][nt][i] + bb;
        outf[(size_t)row * NC_EMB + col] = v;
        outb[(size_t)row * NC_EMB + col] = f2bf(v);
      }
    }
  }
}

__global__ __launch_bounds__(256) void conv_k(const float* __restrict__ src,
                                              u16* __restrict__ dst, int n4)
{
  const int g = blockIdx.x * 256 + threadIdx.x;
  if (g < n4) {
    float4 v = ((const float4*)src)[g];
    ((ushort4*)dst)[g] = make_ushort4(f2bf(v.x), f2bf(v.y), f2bf(v.z), f2bf(v.w));
  }
}

// Build GATE-INTERLEAVED U_big[l][1024][640] (bf16) + fused f32 biases.
// Row c' = j*8+g: g<4 -> old row g*128+j (f-gates); g=4/5/6 -> old rows
// 512+j / 640+j / 768+j (i/u/o); g=7 -> zero pad. W_w fold: wr = j (g<4),
// 128+j / 256+j / 384+j (g=4/5/6).
__global__ __launch_bounds__(256) void prep_k(
    const float* __restrict__ Uf_w, const float* __restrict__ Uf_b,
    const float* __restrict__ Uiuo_w, const float* __restrict__ Uiuo_b,
    const float* __restrict__ W_w, const float* __restrict__ W_b,
    u16* __restrict__ Ubig, float* __restrict__ biasbig)
{
  const int l = blockIdx.y;
  const int e = blockIdx.x * 256 + threadIdx.x;   // < 1024*640
  const int cp = e / KD_STEP;
  const int k = e % KD_STEP;
  const int j = cp >> 3, g = cp & 7;
  float v = 0.f;
  if (g != 7) {
    const int oldc = (g < 4) ? (g * 128 + j) : (512 + (g - 4) * 128 + j);
    if (k < 512) {
      v = (oldc < 512) ? Uf_w[((size_t)l * 512 + oldc) * 512 + k]
                       : Uiuo_w[((size_t)l * 384 + (oldc - 512)) * 512 + k];
    } else {
      const int wr = (oldc < 512) ? (oldc & 127) : (128 + (oldc - 512));
      v = W_w[((size_t)l * 512 + wr) * 128 + (k - 512)];
    }
  }
  Ubig[((size_t)l * NCP + cp) * KD_STEP + k] = f2bf(v);
  if (e < NCP) {
    const int jj = e >> 3, gg = e & 7;
    float b = 0.f;
    if (gg != 7) {
      const int oldc = (gg < 4) ? (gg * 128 + jj) : (512 + (gg - 4) * 128 + jj);
      const int wr = (oldc < 512) ? (oldc & 127) : (128 + (oldc - 512));
      b = ((oldc < 512) ? Uf_b[l * 512 + oldc] : Uiuo_b[l * 384 + (oldc - 512)])
          + W_b[l * 512 + wr];
    }
    biasbig[l * NCP + e] = b;
  }
}

// Output (FLOAT32): hx = tile(t_final,2), cx = tile(c_final,2).
__global__ __launch_bounds__(256) void fin_k(
    const float* __restrict__ t_fin, const float* __restrict__ c_fin,
    float* __restrict__ out)
{
  const size_t NH = (size_t)NNODE * HD;
  const size_t g = (size_t)blockIdx.x * 256 + threadIdx.x;
  const float h = t_fin[g];
  const float c = c_fin[g];
  out[g] = h;
  out[NH + g] = h;
  out[2 * NH + g] = c;
  out[3 * NH + g] = c;
}

extern "C" void kernel_launch(void* const* d_in, const int* in_sizes, int n_in,
                              void* d_out, int out_size, void* d_ws, size_t ws_size,
                              hipStream_t stream)
{
  (void)in_sizes; (void)n_in; (void)out_size; (void)ws_size;
  const int*   tokens  = (const int*)d_in[0];
  const int*   indices = (const int*)d_in[1];
  const float* E       = (const float*)d_in[2];
  const float* lin_w   = (const float*)d_in[3];
  const float* lin_b   = (const float*)d_in[4];
  const float* Uf_w    = (const float*)d_in[5];
  const float* Uf_b    = (const float*)d_in[6];
  const float* Uiuo_w  = (const float*)d_in[7];
  const float* Uiuo_b  = (const float*)d_in[8];
  const float* W_w     = (const float*)d_in[9];
  const float* W_b     = (const float*)d_in[10];
  float* out = (float*)d_out;   // FLOAT32 output

  const size_t NH = (size_t)NNODE * HD;

  char* ws = (char*)d_ws;
  size_t off = 0;
  auto alloc = [&](size_t bytes) -> void* {
    void* p = ws + off;
    off = (off + bytes + 255) & ~(size_t)255;
    return p;
  };
  u16*   Ubig    = (u16*)alloc((size_t)2 * NCP * KD_STEP * 2);
  float* biasbig = (float*)alloc(2 * NCP * 4);
  u16*   Ebf     = (u16*)alloc((size_t)50000 * HD * 2);
  u16*   Lbf     = (u16*)alloc((size_t)HD * KD_EMB * 2);
  float* tA      = (float*)alloc(NH * 4);
  float* tB      = (float*)alloc(NH * 4);
  u16*   tbfA    = (u16*)alloc(NH * 2);
  u16*   tbfB    = (u16*)alloc(NH * 2);
  u16*   h0a     = (u16*)alloc(NH * 2);
  u16*   h0b     = (u16*)alloc(NH * 2);
  u16*   h1a     = (u16*)alloc(NH * 2);
  u16*   h1b     = (u16*)alloc(NH * 2);
  float* c0a     = (float*)alloc(NH * 4);
  float* c0b     = (float*)alloc(NH * 4);
  float* c1a     = (float*)alloc(NH * 4);
  float* c1b     = (float*)alloc(NH * 4);
  u16*   zbuf    = (u16*)alloc(512);

  u16*   h0[2] = {h0a, h0b};
  u16*   h1[2] = {h1a, h1b};
  float* c0[2] = {c0a, c0b};
  float* c1[2] = {c1a, c1b};

  hipMemsetAsync(zbuf, 0, 512, stream);
  hipMemsetAsync(h0[0], 0, NH * 2, stream);
  hipMemsetAsync(h1[0], 0, NH * 2, stream);
  hipMemsetAsync(c0[0], 0, NH * 4, stream);
  hipMemsetAsync(c1[0], 0, NH * 4, stream);
  prep_k<<<dim3(NCP * KD_STEP / 256, 2), 256, 0, stream>>>(
      Uf_w, Uf_b, Uiuo_w, Uiuo_b, W_w, W_b, Ubig, biasbig);
  conv_k<<<dim3((50000 * HD / 4 + 255) / 256), 256, 0, stream>>>(E, Ebf, 50000 * HD / 4);
  conv_k<<<dim3((HD * KD_EMB / 4 + 255) / 256), 256, 0, stream>>>(lin_w, Lbf, HD * KD_EMB / 4);

  for (int d = 0; d < DD; ++d) {
    const int ri = d & 1, wi = (d + 1) & 1;
    const int* idxd = indices + (size_t)d * NNODE * KCH;
    const int* tokd = tokens + (size_t)d * NNODE * LTOK;

    // tA (f32) + tbfA (bf16) = gather(Ebf, tokens[d]) @ Lbf^T + lin_b
    gemm_emb_k<<<dim3(NNODE / 64), 256, 0, stream>>>(
        Ebf, tokd, Lbf, lin_b, tA, tbfA);

    // layer 0: reads tA/tbfA, writes tB/tbfB
    gemm_fused_k<<<dim3((NNODE / BM) * (NCP / BN)), 512, 0, stream>>>(
        h0[ri], tbfA, idxd, Ubig, biasbig,
        c0[ri], c0[wi], h0[wi], tA, tB, tbfB, zbuf);
    // layer 1: reads tB/tbfB, writes tA/tbfA
    gemm_fused_k<<<dim3((NNODE / BM) * (NCP / BN)), 512, 0, stream>>>(
        h1[ri], tbfB, idxd, Ubig + (size_t)NCP * KD_STEP, biasbig + NCP,
        c1[ri], c1[wi], h1[wi], tB, tA, tbfA, zbuf);
  }
  // after d=11: tA = t_final, c1[0] = c_final
  fin_k<<<dim3((int)(NH / 256)), 256, 0, stream>>>(tA, c1[0], out);
}